// Round 1
// baseline (588.669 us; speedup 1.0000x reference)
//
#include <hip/hip_runtime.h>
#include <math.h>

namespace {
constexpr int Bn = 2, Cn = 32, Hn = 128, Wn = 128;
constexpr int Pn = Hn * Wn;         // 16384 pixels per batch
constexpr int Nn = Bn * Pn;         // 32768 patches
constexpr int Ln = 7, LLn = 49, PADn = 3;
constexpr int OUT0 = Bn * Cn * Pn;  // offset of att_mp inside d_out (1,048,576)
}

// Pre-contract w1 (32->32, 3x3) with w2 (1x1, 32->1):
// wk[c*9 + di*3 + dj] = sum_o w2[o] * w1[o][c][di][dj];  wk[288] = w2.b1 + b2
__global__ void prep_kernel(const float* __restrict__ w1,
                            const float* __restrict__ b1,
                            const float* __restrict__ w2,
                            const float* __restrict__ b2,
                            float* __restrict__ wk) {
    int t = threadIdx.x;
    if (t < 288) {
        int c = t / 9, r = t % 9;
        float s = 0.f;
#pragma unroll
        for (int o = 0; o < 32; ++o) s += w2[o] * w1[o * 288 + c * 9 + r];
        wk[t] = s;
    } else if (t == 288) {
        float s = b2[0];
#pragma unroll
        for (int o = 0; o < 32; ++o) s += w2[o] * b1[o];
        wk[288] = s;
    }
}

// att[n, pos] = sigmoid( sum_{c,di,dj valid} x[b,c,h+ii-3,w+jj-3] * wk[c,di,dj] + bk )
// pos is uniform per block (pos-major layout): all patch-padding validity checks
// are wave-uniform; x reads are lane-consecutive (coalesced).
__global__ __launch_bounds__(256) void att_kernel(const float* __restrict__ x,
                                                  const float* __restrict__ wk,
                                                  float* __restrict__ att_out) {
    __shared__ float wks[289];
    int t = threadIdx.x;
    for (int k = t; k < 289; k += 256) wks[k] = wk[k];
    __syncthreads();

    int pos = blockIdx.x >> 7;                 // 0..48, uniform per block
    int n = ((blockIdx.x & 127) << 8) + t;     // 0..32767, lane-consecutive
    int b = n >> 14;
    int p = n & (Pn - 1);
    int h = p >> 7, w = p & (Wn - 1);
    int i = pos / 7, j = pos % 7;

    const float* xb = x + ((long)b << 19);
    float s = wks[288];
#pragma unroll 1
    for (int c = 0; c < Cn; ++c) {
        const float* xc = xb + (c << 14);
        const float* wc = &wks[c * 9];
#pragma unroll
        for (int di = 0; di < 3; ++di) {
            int ii = i + di - 1;               // patch-local row of the 3x3 tap
            if ((unsigned)ii >= 7u) continue;  // conv zero-pads the 7x7 patch
            int gi = h + ii - PADn;            // global image row
            if ((unsigned)gi >= (unsigned)Hn) continue;
            const float* xr = xc + (gi << 7);
#pragma unroll
            for (int dj = 0; dj < 3; ++dj) {
                int jj = j + dj - 1;
                if ((unsigned)jj >= 7u) continue;
                int gj = w + jj - PADn;
                if ((unsigned)gj >= (unsigned)Wn) continue;
                s += xr[gj] * wc[di * 3 + dj];
            }
        }
    }
    float a = 1.f / (1.f + expf(-s));
    att_out[n * LLn + pos] = a;                // att_mp output [B,1,P,7,7]
}

// out[n,o] = b3[o] + sum_{i,j valid} (1+att[n,ij]) * sum_c x[b,c,gi,gj]*w3[o,c,ij]
// o-major layout: w3/b3 reads are wave-uniform (scalar broadcast); x reads and
// the output store are lane-consecutive (coalesced).
__global__ __launch_bounds__(256) void out_kernel(const float* __restrict__ x,
                                                  const float* __restrict__ att,
                                                  const float* __restrict__ w3,
                                                  const float* __restrict__ b3,
                                                  float* __restrict__ out) {
    int t = threadIdx.x;
    int o = blockIdx.x >> 7;                   // 0..31, uniform per block
    int n = ((blockIdx.x & 127) << 8) + t;
    int b = n >> 14;
    int p = n & (Pn - 1);
    int h = p >> 7, w = p & (Wn - 1);

    const float* xb = x + ((long)b << 19);
    const float* attn = att + (long)n * LLn;
    const float* w3o = w3 + o * (Cn * LLn);

    float acc = b3[o];
#pragma unroll 1
    for (int i = 0; i < Ln; ++i) {
        int gi = h + i - PADn;
        if ((unsigned)gi >= (unsigned)Hn) continue;   // x_pad is zero there
#pragma unroll 1
        for (int j = 0; j < Ln; ++j) {
            int gj = w + j - PADn;
            if ((unsigned)gj >= (unsigned)Wn) continue;
            float g = 1.f + attn[i * 7 + j];
            const float* xp = xb + (gi << 7) + gj;
            const float* wp = w3o + i * 7 + j;
            float partial = 0.f;
#pragma unroll
            for (int c = 0; c < Cn; ++c)
                partial += xp[(long)c << 14] * wp[c * LLn];
            acc += partial * g;
        }
    }
    // output[b][o][p]
    out[((long)b << 19) + (o << 14) + p] = acc;
}

extern "C" void kernel_launch(void* const* d_in, const int* in_sizes, int n_in,
                              void* d_out, int out_size, void* d_ws, size_t ws_size,
                              hipStream_t stream) {
    const float* x  = (const float*)d_in[0];
    const float* w1 = (const float*)d_in[1];
    const float* b1 = (const float*)d_in[2];
    const float* w2 = (const float*)d_in[3];
    const float* b2 = (const float*)d_in[4];
    const float* w3 = (const float*)d_in[5];
    const float* b3 = (const float*)d_in[6];
    // d_in[7] = local_scale (7) — hardcoded in the constants above.

    float* out = (float*)d_out;
    float* att_out = out + OUT0;   // att_mp region of d_out (output #2)
    float* wk = (float*)d_ws;      // 289 floats of scratch

    prep_kernel<<<1, 320, 0, stream>>>(w1, b1, w2, b2, wk);
    att_kernel<<<49 * 128, 256, 0, stream>>>(x, wk, att_out);
    out_kernel<<<32 * 128, 256, 0, stream>>>(x, att_out, w3, b3, out);
}

// Round 3
// 101.326 us; speedup vs baseline: 5.8097x; 5.8097x over previous
//
#include <hip/hip_runtime.h>
#include <math.h>

typedef __attribute__((ext_vector_type(8))) short bf16x8;
typedef __attribute__((ext_vector_type(4))) float f32x4;
typedef __attribute__((ext_vector_type(4))) unsigned int u32x4;

namespace {
constexpr int OUT0 = 2 * 32 * 16384;  // offset of att_mp inside d_out
}

// f32 -> bf16 round-to-nearest-even, returned in low 16 bits.
__device__ __forceinline__ unsigned int f32_bf16(float f) {
  unsigned int u = __builtin_bit_cast(unsigned int, f);
  u += 0x7fffu + ((u >> 16) & 1u);
  return u >> 16;
}
// pack two f32 into bf16x2 dword: lo in [15:0], hi in [31:16]
__device__ __forceinline__ unsigned int pack_bf16x2(float lo, float hi) {
  return f32_bf16(lo) | (f32_bf16(hi) << 16);
}

// Prep: (a) pack w3 into per-lane bf16 B-fragments for mfma_f32_16x16x32_bf16:
//   frag (ij, nt): lane l, dword d holds bf16 pair B[k0][o],B[k0+1][o],
//   k(=c) = (l>>4)*8 + 2d, o = nt*16 + (l&15).  25088 dwords total.
// (b) wk[c*9+dd] = sum_o w2[o]*w1[o,c,dd]; wk[288] = w2.b1 + b2.
__global__ __launch_bounds__(256) void prep_kernel(
    const float* __restrict__ w1, const float* __restrict__ b1,
    const float* __restrict__ w2, const float* __restrict__ b2,
    const float* __restrict__ w3,
    float* __restrict__ wk, unsigned int* __restrict__ w3f) {
  int t = threadIdx.x, blk = blockIdx.x;
  if (blk < 98) {
    int f = blk * 256 + t;          // dword index, f < 25088
    int d = f & 3;
    int lane = (f >> 2) & 63;
    int nt = (f >> 8) & 1;
    int ij = f >> 9;                // 0..48
    int o = nt * 16 + (lane & 15);
    int k0 = ((lane >> 4) << 3) + 2 * d;   // c of low half
    float f0 = w3[o * 1568 + k0 * 49 + ij];
    float f1 = w3[o * 1568 + (k0 + 1) * 49 + ij];
    w3f[f] = pack_bf16x2(f0, f1);
  } else {
    int k = (blk - 98) * 256 + t;
    if (k < 288) {
      int c = k / 9, r = k - c * 9;
      float s = 0.f;
#pragma unroll
      for (int o = 0; o < 32; ++o) s += w2[o] * w1[o * 288 + c * 9 + r];
      wk[k] = s;
    } else if (k == 288) {
      float s = b2[0];
#pragma unroll
      for (int o = 0; o < 32; ++o) s += w2[o] * b1[o];
      wk[288] = s;
    }
  }
}

// Fused kernel: one 8x8 pixel tile per block (512 blocks, 256 threads).
__global__ __launch_bounds__(256) void fused_kernel(
    const float* __restrict__ x, const float* __restrict__ wk,
    const unsigned int* __restrict__ w3f, const float* __restrict__ b3,
    float* __restrict__ out, float* __restrict__ att_out) {
  // xs: x tile+halo, channel-contiguous: xs[sp*36 + c], sp = ly*16+lx (16x16).
  // stride 36 dwords -> 16B-aligned float4 slices, <=2-way banks.
  __shared__ float xs[256 * 36];          // 36,864 B
  __shared__ float ys[9 * 272];           //  9,792 B  y[dd][r*17+cc]
  __shared__ float as_[49 * 64];          // 12,544 B  att[pos][px]; reused for epilogue
  __shared__ float wks[292];              //  1,168 B

  int t = threadIdx.x;
  int bi = blockIdx.x;
  int b = bi >> 8;
  int tile = bi & 255;
  int y0 = (tile >> 4) << 3, x0 = (tile & 15) << 3;
  const float* xb = x + ((long)b << 19);

  for (int k = t; k < 289; k += 256) wks[k] = wk[k];

  // ---- phase 1: stage x tile + halo(4), zero-padded outside image ----
#pragma unroll
  for (int it = 0; it < 32; ++it) {
    int idx = it * 256 + t;
    int c = idx >> 8, rem = idx & 255;
    int ly = rem >> 4, lx = rem & 15;
    int gy = y0 + ly - 4, gx = x0 + lx - 4;
    float v = 0.f;
    if ((unsigned)gy < 128u && (unsigned)gx < 128u)
      v = xb[(c << 14) + (gy << 7) + gx];
    xs[rem * 36 + c] = v;
  }
  __syncthreads();

  // ---- phase 1b: y[dd][r][cc] = sum_c x[c][r][cc] * wk[c][dd] ----
  {
    int r = t >> 4, cc = t & 15;
    float s[9];
#pragma unroll
    for (int dd = 0; dd < 9; ++dd) s[dd] = 0.f;
#pragma unroll
    for (int c4 = 0; c4 < 8; ++c4) {
      f32x4 xv = *reinterpret_cast<const f32x4*>(&xs[t * 36 + c4 * 4]);
#pragma unroll
      for (int e = 0; e < 4; ++e) {
        int c = c4 * 4 + e;
#pragma unroll
        for (int dd = 0; dd < 9; ++dd) s[dd] += xv[e] * wks[c * 9 + dd];
      }
    }
#pragma unroll
    for (int dd = 0; dd < 9; ++dd) ys[dd * 272 + r * 17 + cc] = s[dd];
  }
  __syncthreads();

  // ---- phase 2: att[pos][px] = sigmoid(bk + sum_{valid taps} y) ----
  {
    int px = t & 63, wv = t >> 6;
    int py = px >> 3, pxl = px & 7;
    long n = (long)(b << 14) + ((y0 + py) << 7) + x0 + pxl;
#pragma unroll 1
    for (int it = 0; it < 13; ++it) {
      int pos = wv * 13 + it;
      if (pos < 49) {
        int i = pos / 7, j = pos - i * 7;
        float s = wks[288];
#pragma unroll
        for (int di = 0; di < 3; ++di) {
          int ii = i + di - 1;
          if ((unsigned)ii >= 7u) continue;
#pragma unroll
          for (int dj = 0; dj < 3; ++dj) {
            int jj = j + dj - 1;
            if ((unsigned)jj >= 7u) continue;
            s += ys[(di * 3 + dj) * 272 + (py + ii + 1) * 17 + (pxl + jj + 1)];
          }
        }
        float a = 1.f / (1.f + expf(-s));
        as_[pos * 64 + px] = a;
        att_out[n * 49 + pos] = a;
      }
    }
  }
  __syncthreads();

  // ---- phase 3: MFMA over 49 taps, K=32 channels each ----
  int lane = t & 63, wv = t >> 6;
  int ml = lane & 15, q = lane >> 4;
  int px = wv * 16 + ml;                 // A-row pixel this lane feeds
  int py = px >> 3, pxl = px & 7;
  int cb = q << 3;                       // this lane's k(=c) base
  f32x4 acc0 = {0.f, 0.f, 0.f, 0.f}, acc1 = {0.f, 0.f, 0.f, 0.f};
  const unsigned int* bptr = w3f + (lane << 2);
#pragma unroll 1
  for (int i = 0; i < 7; ++i) {
    int rb = (py + i + 1) * 16;
#pragma unroll
    for (int j = 0; j < 7; ++j) {
      int ij = i * 7 + j;
      u32x4 bw0 = *reinterpret_cast<const u32x4*>(bptr + (ij * 2 + 0) * 256);
      u32x4 bw1 = *reinterpret_cast<const u32x4*>(bptr + (ij * 2 + 1) * 256);
      float g = 1.f + as_[ij * 64 + px];
      int sp = rb + pxl + j + 1;
      const f32x4 xv0 = *reinterpret_cast<const f32x4*>(&xs[sp * 36 + cb]);
      const f32x4 xv1 = *reinterpret_cast<const f32x4*>(&xs[sp * 36 + cb + 4]);
      u32x4 av;
      av[0] = pack_bf16x2(xv0[0] * g, xv0[1] * g);
      av[1] = pack_bf16x2(xv0[2] * g, xv0[3] * g);
      av[2] = pack_bf16x2(xv1[0] * g, xv1[1] * g);
      av[3] = pack_bf16x2(xv1[2] * g, xv1[3] * g);
      bf16x8 af = __builtin_bit_cast(bf16x8, av);
      acc0 = __builtin_amdgcn_mfma_f32_16x16x32_bf16(
          af, __builtin_bit_cast(bf16x8, bw0), acc0, 0, 0, 0);
      acc1 = __builtin_amdgcn_mfma_f32_16x16x32_bf16(
          af, __builtin_bit_cast(bf16x8, bw1), acc1, 0, 0, 0);
    }
  }
  __syncthreads();   // att reads done; reuse as_ for transpose

  // ---- epilogue: D layout col=lane&15(=o), row=q*4+reg(=px) -> LDS [o][px] ----
  {
    float bv0 = b3[ml], bv1 = b3[16 + ml];
#pragma unroll
    for (int r = 0; r < 4; ++r) {
      int pxd = (wv << 4) + (q << 2) + r;
      as_[ml * 65 + pxd] = acc0[r] + bv0;
      as_[(16 + ml) * 65 + pxd] = acc1[r] + bv1;
    }
  }
  __syncthreads();
#pragma unroll
  for (int rep = 0; rep < 8; ++rep) {
    int idx = rep * 256 + t;
    int o = idx >> 6, pxs = idx & 63;
    out[((long)b << 19) + (o << 14) + ((y0 + (pxs >> 3)) << 7) + x0 + (pxs & 7)]
        = as_[o * 65 + pxs];
  }
}

extern "C" void kernel_launch(void* const* d_in, const int* in_sizes, int n_in,
                              void* d_out, int out_size, void* d_ws, size_t ws_size,
                              hipStream_t stream) {
  const float* x  = (const float*)d_in[0];
  const float* w1 = (const float*)d_in[1];
  const float* b1 = (const float*)d_in[2];
  const float* w2 = (const float*)d_in[3];
  const float* b2 = (const float*)d_in[4];
  const float* w3 = (const float*)d_in[5];
  const float* b3 = (const float*)d_in[6];

  float* out = (float*)d_out;
  float* att_out = out + OUT0;
  float* wk = (float*)d_ws;                                // 289 floats
  unsigned int* w3f = (unsigned int*)((char*)d_ws + 4096); // 25088 dwords

  prep_kernel<<<100, 256, 0, stream>>>(w1, b1, w2, b2, w3, wk, w3f);
  fused_kernel<<<512, 256, 0, stream>>>(x, wk, w3f, b3, out, att_out);
}

// Round 4
// 96.725 us; speedup vs baseline: 6.0860x; 1.0476x over previous
//
#include <hip/hip_runtime.h>
#include <math.h>

typedef __attribute__((ext_vector_type(8))) short bf16x8;
typedef __attribute__((ext_vector_type(4))) float f32x4;
typedef __attribute__((ext_vector_type(4))) unsigned int u32x4;

namespace {
constexpr int OUT0 = 2 * 32 * 16384;  // offset of att_mp inside d_out
}

// f32 -> bf16 RNE, result in the value's high 16 bits (pre-shift form).
__device__ __forceinline__ unsigned int bf16_rnd(float f) {
  unsigned int u = __builtin_bit_cast(unsigned int, f);
  return u + 0x7fffu + ((u >> 16) & 1u);
}
// pack two f32 into bf16x2 dword via v_perm_b32: bytes [lo.b2,lo.b3,hi.b2,hi.b3]
__device__ __forceinline__ unsigned int pack_bf16x2(float lo, float hi) {
  return __builtin_amdgcn_perm(bf16_rnd(hi), bf16_rnd(lo), 0x07060302u);
}

// Prep: (a) pack w3 into per-lane bf16 B-fragments for mfma_f32_16x16x32_bf16:
//   frag (ij, nt): lane l, dword d holds bf16 pair B[k0][o],B[k0+1][o],
//   k(=c) = (l>>4)*8 + 2d, o = nt*16 + (l&15).  25088 dwords total.
// (b) wk[c*9+dd] = sum_o w2[o]*w1[o,c,dd]; wk[288] = w2.b1 + b2.
__global__ __launch_bounds__(256) void prep_kernel(
    const float* __restrict__ w1, const float* __restrict__ b1,
    const float* __restrict__ w2, const float* __restrict__ b2,
    const float* __restrict__ w3,
    float* __restrict__ wk, unsigned int* __restrict__ w3f) {
  int t = threadIdx.x, blk = blockIdx.x;
  if (blk < 98) {
    int f = blk * 256 + t;          // dword index, f < 25088
    int d = f & 3;
    int lane = (f >> 2) & 63;
    int nt = (f >> 8) & 1;
    int ij = f >> 9;                // 0..48
    int o = nt * 16 + (lane & 15);
    int k0 = ((lane >> 4) << 3) + 2 * d;   // c of low half
    float f0 = w3[o * 1568 + k0 * 49 + ij];
    float f1 = w3[o * 1568 + (k0 + 1) * 49 + ij];
    w3f[f] = pack_bf16x2(f0, f1);
  } else {
    int k = (blk - 98) * 256 + t;
    if (k < 288) {
      int c = k / 9, r = k - c * 9;
      float s = 0.f;
#pragma unroll
      for (int o = 0; o < 32; ++o) s += w2[o] * w1[o * 288 + c * 9 + r];
      wk[k] = s;
    } else if (k == 288) {
      float s = b2[0];
#pragma unroll
      for (int o = 0; o < 32; ++o) s += w2[o] * b1[o];
      wk[288] = s;
    }
  }
}

// Fused kernel: one 8x8 pixel tile per block (512 blocks, 256 threads).
__global__ __launch_bounds__(256) void fused_kernel(
    const float* __restrict__ x, const float* __restrict__ wk,
    const unsigned int* __restrict__ w3f, const float* __restrict__ b3,
    float* __restrict__ out, float* __restrict__ att_out) {
  // xs: x tile+halo, channel-contiguous: xs[sp*36 + c], sp = ly*16+lx (16x16).
  __shared__ float xs[256 * 36];          // 36,864 B
  __shared__ float ys[9 * 272];           //  9,792 B  y[dd][r*17+cc]
  __shared__ float as_[49 * 65];          // 12,740 B  att[pos*65+px]; reused in epilogue
  __shared__ float wks[292];              //  1,168 B

  int t = threadIdx.x;
  int bi = blockIdx.x;
  int b = bi >> 8;
  int tile = bi & 255;
  int y0 = (tile >> 4) << 3, x0 = (tile & 15) << 3;
  const float* xb = x + ((long)b << 19);

  for (int k = t; k < 289; k += 256) wks[k] = wk[k];

  // ---- phase 1: stage x tile + halo(4) via float4; tile geometry makes each
  // 4-float segment fully inside or fully outside the image (uniform check).
#pragma unroll
  for (int it = 0; it < 8; ++it) {
    int idx = it * 256 + t;
    int c = idx >> 6;                 // 4 channels per iteration
    int r64 = idx & 63;
    int row = r64 >> 2, seg = r64 & 3;
    int gy = y0 + row - 4;
    int gxs = x0 + (seg << 2) - 4;
    f32x4 v = {0.f, 0.f, 0.f, 0.f};
    if ((unsigned)gy < 128u && (unsigned)gxs < 128u)
      v = *reinterpret_cast<const f32x4*>(xb + (c << 14) + (gy << 7) + gxs);
    int sp = (row << 4) + (seg << 2);
#pragma unroll
    for (int e = 0; e < 4; ++e) xs[(sp + e) * 36 + c] = v[e];
  }
  __syncthreads();

  // ---- phase 1b: y[dd][r][cc] = sum_c x[c][r][cc] * wk[c][dd] ----
  {
    int r = t >> 4, cc = t & 15;
    float s[9];
#pragma unroll
    for (int dd = 0; dd < 9; ++dd) s[dd] = 0.f;
#pragma unroll
    for (int c4 = 0; c4 < 8; ++c4) {
      f32x4 xv = *reinterpret_cast<const f32x4*>(&xs[t * 36 + c4 * 4]);
#pragma unroll
      for (int e = 0; e < 4; ++e) {
        int c = c4 * 4 + e;
#pragma unroll
        for (int dd = 0; dd < 9; ++dd) s[dd] += xv[e] * wks[c * 9 + dd];
      }
    }
#pragma unroll
    for (int dd = 0; dd < 9; ++dd) ys[dd * 272 + r * 17 + cc] = s[dd];
  }
  __syncthreads();

  // ---- phase 2: att[pos][px] = sigmoid(bk + sum_{valid taps} y) -> LDS only ----
  {
    int px = t & 63, wv = t >> 6;
    int py = px >> 3, pxl = px & 7;
#pragma unroll 1
    for (int it = 0; it < 13; ++it) {
      int pos = wv * 13 + it;
      if (pos < 49) {
        int i = pos / 7, j = pos - i * 7;
        float s = wks[288];
#pragma unroll
        for (int di = 0; di < 3; ++di) {
          int ii = i + di - 1;
          if ((unsigned)ii >= 7u) continue;
#pragma unroll
          for (int dj = 0; dj < 3; ++dj) {
            int jj = j + dj - 1;
            if ((unsigned)jj >= 7u) continue;
            s += ys[(di * 3 + dj) * 272 + (py + ii + 1) * 17 + (pxl + jj + 1)];
          }
        }
        as_[pos * 65 + px] = 1.f / (1.f + expf(-s));
      }
    }
  }
  __syncthreads();

  // ---- phase 2.5: coalesced att_out stores. Per pixel-row the block owns a
  // contiguous 392-float run: att_out[nbase*49 + rem], rem = pxl*49+pos. ----
  {
#pragma unroll 1
    for (int it = 0; it < 13; ++it) {
      int f = it * 256 + t;
      if (f < 3136) {
        int row = f / 392;
        int rem = f - row * 392;
        int pxl = rem / 49;
        int pos = rem - pxl * 49;
        long base = ((long)(b << 14) + ((y0 + row) << 7) + x0) * 49;
        att_out[base + rem] = as_[pos * 65 + (row << 3) + pxl];
      }
    }
  }

  // ---- phase 3: MFMA over 49 taps, K=32 channels each ----
  int lane = t & 63, wv = t >> 6;
  int ml = lane & 15, q = lane >> 4;
  int px = wv * 16 + ml;                 // A-row pixel this lane feeds
  int py = px >> 3, pxl = px & 7;
  int cb = q << 3;                       // this lane's k(=c) base
  f32x4 acc0 = {0.f, 0.f, 0.f, 0.f}, acc1 = {0.f, 0.f, 0.f, 0.f};
  const unsigned int* bptr = w3f + (lane << 2);
#pragma unroll 1
  for (int i = 0; i < 7; ++i) {
    int rb = (py + i + 1) * 16;
#pragma unroll
    for (int j = 0; j < 7; ++j) {
      int ij = i * 7 + j;
      u32x4 bw0 = *reinterpret_cast<const u32x4*>(bptr + (ij * 2 + 0) * 256);
      u32x4 bw1 = *reinterpret_cast<const u32x4*>(bptr + (ij * 2 + 1) * 256);
      float g = 1.f + as_[ij * 65 + px];
      int sp = rb + pxl + j + 1;
      const f32x4 xv0 = *reinterpret_cast<const f32x4*>(&xs[sp * 36 + cb]);
      const f32x4 xv1 = *reinterpret_cast<const f32x4*>(&xs[sp * 36 + cb + 4]);
      u32x4 av;
      av[0] = pack_bf16x2(xv0[0] * g, xv0[1] * g);
      av[1] = pack_bf16x2(xv0[2] * g, xv0[3] * g);
      av[2] = pack_bf16x2(xv1[0] * g, xv1[1] * g);
      av[3] = pack_bf16x2(xv1[2] * g, xv1[3] * g);
      bf16x8 af = __builtin_bit_cast(bf16x8, av);
      acc0 = __builtin_amdgcn_mfma_f32_16x16x32_bf16(
          af, __builtin_bit_cast(bf16x8, bw0), acc0, 0, 0, 0);
      acc1 = __builtin_amdgcn_mfma_f32_16x16x32_bf16(
          af, __builtin_bit_cast(bf16x8, bw1), acc1, 0, 0, 0);
    }
  }
  __syncthreads();   // att reads + stores done; reuse as_ for transpose

  // ---- epilogue: D layout col=lane&15(=o), row=q*4+reg(=px) -> LDS [o][px] ----
  {
    float bv0 = b3[ml], bv1 = b3[16 + ml];
#pragma unroll
    for (int r = 0; r < 4; ++r) {
      int pxd = (wv << 4) + (q << 2) + r;
      as_[ml * 65 + pxd] = acc0[r] + bv0;
      as_[(16 + ml) * 65 + pxd] = acc1[r] + bv1;
    }
  }
  __syncthreads();
#pragma unroll
  for (int rep = 0; rep < 8; ++rep) {
    int idx = rep * 256 + t;
    int o = idx >> 6, pxs = idx & 63;
    out[((long)b << 19) + (o << 14) + ((y0 + (pxs >> 3)) << 7) + x0 + (pxs & 7)]
        = as_[o * 65 + pxs];
  }
}

extern "C" void kernel_launch(void* const* d_in, const int* in_sizes, int n_in,
                              void* d_out, int out_size, void* d_ws, size_t ws_size,
                              hipStream_t stream) {
  const float* x  = (const float*)d_in[0];
  const float* w1 = (const float*)d_in[1];
  const float* b1 = (const float*)d_in[2];
  const float* w2 = (const float*)d_in[3];
  const float* b2 = (const float*)d_in[4];
  const float* w3 = (const float*)d_in[5];
  const float* b3 = (const float*)d_in[6];

  float* out = (float*)d_out;
  float* att_out = out + OUT0;
  float* wk = (float*)d_ws;                                // 289 floats
  unsigned int* w3f = (unsigned int*)((char*)d_ws + 4096); // 25088 dwords

  prep_kernel<<<100, 256, 0, stream>>>(w1, b1, w2, b2, w3, wk, w3f);
  fused_kernel<<<512, 256, 0, stream>>>(x, wk, w3f, b3, out, att_out);
}